// Round 8
// baseline (80.605 us; speedup 1.0000x reference)
//
#include <hip/hip_runtime.h>

// Signature kernel (dyadic order 1, sigma=1) for xs:(16,128,8), ys:(16,128,8) f32.
// One block (256 thr) per pair.
// Phase 1 (4 waves): coefficients straight from dots (K never stored); row 2l+2's
//   K-values come from lane l+1 via DPP wave_shl1 (saves a dot+expf per column).
// Phase 2 (wave 0, zero barriers): register wavefront, lane l owns PDE rows
//   4l+1..4l+4 at col j = s-2l; one ds_read_b128 coeff quad per 2-substep body.
//   DPP wave_shr1 HOISTED to substep start consuming the PREVIOUS substep's n3
//   (kills VALU->DPP hazard wait-states); h1_s = sh_{s-1}, h2_s = sh_{s-2}.
//   OOB bodies read a (1,1,1,1) slot -> inert, no predication.
// Model (R3..R7 consistent): the serial wave is ISSUE-bound; time ~ instr count.

#define NB 16

__device__ __forceinline__ float wave_shr1_or_one(float v) {
    // lane i <- v[lane i-1]; lane 0 <- 1.0f (bound_ctrl=false keeps 'old')
    const int one = 0x3f800000;
    int r = __builtin_amdgcn_update_dpp(one, __float_as_int(v),
                                        0x138 /*wave_shr:1*/, 0xF, 0xF, false);
    return __int_as_float(r);
}

__device__ __forceinline__ float wave_shl1(float v) {
    // lane i <- v[lane i+1]; lane 63 <- old (0, masked out by caller)
    int r = __builtin_amdgcn_update_dpp(0, __float_as_int(v),
                                        0x130 /*wave_shl:1*/, 0xF, 0xF, false);
    return __int_as_float(r);
}

__global__ __launch_bounds__(256)
void sigkernel_kernel(const float* __restrict__ xs,
                      const float* __restrict__ ys,
                      float* __restrict__ out)
{
    __shared__ float sx[128][9];
    __shared__ float sy[128 * 8];
    __shared__ float xsq[128];
    __shared__ float ysq[128];
    __shared__ float CF[64 * 128 * 4 + 4];  // coeff quads + trailing (1,1,1,1) slot

    const int t  = threadIdx.x;
    const int bx = blockIdx.x;
    const int by = blockIdx.y;
    const float* xp = xs + bx * 1024;
    const float* yp = ys + by * 1024;

    for (int e = t; e < 1024; e += 256) {
        sx[e >> 3][e & 7] = xp[e];
        sy[e] = yp[e];
    }
    __syncthreads();

    if (t < 128) {
        float s = 0.f;
        #pragma unroll
        for (int k = 0; k < 8; ++k) s += sx[t][k] * sx[t][k];
        xsq[t] = s;
    } else {
        const int q = t - 128;
        float s = 0.f;
        #pragma unroll
        for (int k = 0; k < 8; ++k) s += sy[q * 8 + k] * sy[q * 8 + k];
        ysq[q] = s;
    }
    if (t == 0) { CF[32768] = 1.f; CF[32769] = 1.f; CF[32770] = 1.f; CF[32771] = 1.f; }
    __syncthreads();

    // ---- phase 1: coefficients from dots; K row 2l+2 via DPP from lane l+1 ----
    {
        const int l = t & 63, w = t >> 6;
        const int r0 = 2 * l, r1 = 2 * l + 1;
        float xr0[8], xr1[8];
        #pragma unroll
        for (int k = 0; k < 8; ++k) { xr0[k] = sx[r0][k]; xr1[k] = sx[r1][k]; }
        const float xq0 = xsq[r0], xq1 = xsq[r1];
        const float4* SYv = (const float4*)sy;
        float4* CFv = (float4*)CF;

        for (int c = 0; c < 4; ++c) {
            const int g = w + 4 * c;        // 0..15 column group
            const int q0 = 8 * g;
            float K0[9], K1[9], K2[9];
            #pragma unroll
            for (int jj = 0; jj < 9; ++jj) {
                int qc = q0 + jj; if (qc > 127) qc = 127;     // only g=15,jj=8
                const float4 ya = SYv[qc * 2];
                const float4 yb = SYv[qc * 2 + 1];
                const float yc = ysq[qc];
                float d0 = xr0[0]*ya.x + xr0[1]*ya.y + xr0[2]*ya.z + xr0[3]*ya.w
                         + xr0[4]*yb.x + xr0[5]*yb.y + xr0[6]*yb.z + xr0[7]*yb.w;
                float d1 = xr1[0]*ya.x + xr1[1]*ya.y + xr1[2]*ya.z + xr1[3]*ya.w
                         + xr1[4]*yb.x + xr1[5]*yb.y + xr1[6]*yb.z + xr1[7]*yb.w;
                K0[jj] = expf(-0.5f * (xq0 + yc - 2.0f * d0));
                K1[jj] = expf(-0.5f * (xq1 + yc - 2.0f * d1));
            }
            #pragma unroll
            for (int jj = 0; jj < 9; ++jj) K2[jj] = wave_shl1(K0[jj]);  // row 2l+2
            #pragma unroll
            for (int m = 0; m < 8; ++m) {
                const int q = q0 + m;
                if (q > 126) continue;                        // only g=15,m=7
                const float dA = K1[m + 1] + K0[m] - K1[m] - K0[m + 1];
                float dB = K2[m + 1] + K1[m] - K2[m] - K1[m + 1];
                if (l == 63) dB = 0.f;                        // dummy row -> inert
                const float iA = 0.25f * dA, iB = 0.25f * dB;
                const float eA = iA * iA * (1.0f / 12.0f);
                const float eB = iB * iB * (1.0f / 12.0f);
                float4 qd;
                qd.x = 1.0f + 0.5f * iA + eA;   // c1 row 2l
                qd.y = 1.0f - eA;               // c2 row 2l
                qd.z = 1.0f + 0.5f * iB + eB;   // c1 row 2l+1
                qd.w = 1.0f - eB;               // c2 row 2l+1
                CFv[l * 128 + ((q + 2 * l) & 127)] = qd;
            }
        }
    }
    __syncthreads();

    // ---- phase 2: waves 1..3 done; wave 0 runs the register wavefront ----
    if (t >= 64) return;

    const int l = t;
    const float4* CFv = (const float4*)CF;

    float cur0 = 1.f, cur1 = 1.f, cur2 = 1.f, cur3 = 1.f;  // rows 4l+1..4l+4, col j-1
    float f1 = 1.f, f2 = 1.f, p3 = 1.f;  // f1=sh_{s-1}, f2=sh_{s-2}, p3=n3_{s-1}

#define LDQ(dst, kk)                                             \
    {                                                            \
        const int q_ = (kk) - l;                                 \
        const int idx = ((unsigned)q_ <= 126u)                   \
                        ? (l * 128 + (((kk) + l) & 127)) : 8192; \
        dst = CFv[idx];                                          \
    }

#define SUBSTEP(c1, c2, c3, c4)                                  \
    {                                                            \
        const float sh = wave_shr1_or_one(p3);  /* old value: no hazard */ \
        const float n0 = (f1 + cur0) * (c1) - f2   * (c2);       \
        const float n1 = (n0 + cur1) * (c1) - cur0 * (c2);       \
        const float n2 = (n1 + cur2) * (c3) - cur1 * (c4);       \
        const float n3 = (n2 + cur3) * (c3) - cur2 * (c4);       \
        cur0 = n0; cur1 = n1; cur2 = n2; cur3 = n3;              \
        f2 = f1; f1 = sh; p3 = n3;                               \
    }

#define BODYQ(Q)                                                 \
    {                                                            \
        const float c1 = Q.x, c2 = Q.y, c3 = Q.z, c4 = Q.w;      \
        SUBSTEP(c1, c2, c3, c4);                                 \
        SUBSTEP(c1, c2, c3, c4);                                 \
    }

    float4 A0, A1, A2;            // 3-deep static prefetch
    LDQ(A0, 0);
    LDQ(A1, 1);
    LDQ(A2, 2);

    // 63 iterations x 3 bodies = 189, + 1 tail = 190 bodies = substeps 1..380
    for (int m = 0; m < 63; ++m) {
        const int k = 3 * m;
        { BODYQ(A0); LDQ(A0, k + 3); }
        { BODYQ(A1); LDQ(A1, k + 4); }
        { BODYQ(A2); LDQ(A2, k + 5); }
    }
    BODYQ(A0);                    // body 189

    // K[254][254]: row 254 = lane 63's second row, finished at substep 380
    if (l == 63) out[bx * NB + by] = cur1;
}

extern "C" void kernel_launch(void* const* d_in, const int* in_sizes, int n_in,
                              void* d_out, int out_size, void* d_ws, size_t ws_size,
                              hipStream_t stream)
{
    const float* xs = (const float*)d_in[0];
    const float* ys = (const float*)d_in[1];
    float* out = (float*)d_out;
    dim3 grid(NB, NB);
    dim3 block(256);
    hipLaunchKernelGGL(sigkernel_kernel, grid, block, 0, stream, xs, ys, out);
}